// Round 1
// baseline (181.246 us; speedup 1.0000x reference)
//
#include <hip/hip_runtime.h>
#include <hip/hip_bf16.h>

#define L_LEN 16384
#define NB 64
#define HD 128
#define NCHUNK 32
#define CHUNK 512
#define TILE_T 128
#define NTILES 4

typedef short bf16x8 __attribute__((ext_vector_type(8)));
typedef float f32x4 __attribute__((ext_vector_type(4)));

__device__ __forceinline__ unsigned short f2bf(float f) {
    unsigned u = __float_as_uint(f);
    return (unsigned short)((u + 0x7FFFu + ((u >> 16) & 1u)) >> 16);  // RNE, finite inputs
}

// tanh-form GELU via sigmoid: x * 1/(1+exp2(x*(c1 + c2*x^2))), c = -2*log2(e)*0.79788456*(1, 0.044715)
__device__ __forceinline__ float gelu_f(float x) {
    float x2 = x * x;
    float f  = x * fmaf(-0.1029437f, x2, -2.30220789f);
    float e  = __builtin_amdgcn_exp2f(f);
    return x * __builtin_amdgcn_rcpf(1.0f + e);
}

// K0: W2 [128][128] f32 -> W2T [n][k] bf16 (transposed) in ws
__global__ __launch_bounds__(256) void k0_prep(const float* __restrict__ W2,
                                               unsigned short* __restrict__ w2t) {
    int i = blockIdx.x * 256 + threadIdx.x;   // 0..16383
    int n = i >> 7, k = i & 127;
    w2t[i] = f2bf(W2[k * 128 + n]);
}

// K1: fused dx -> gelu(dx@W1+b1) -> gelu(h1@W2+b2) -> per-chunk sum/max partials
__global__ __launch_bounds__(256) void k1_fused(
    const float* __restrict__ x,
    const float* __restrict__ W1,
    const float* __restrict__ b1,
    const unsigned short* __restrict__ w2t,
    const float* __restrict__ b2,
    float* __restrict__ psum,
    float* __restrict__ pmaxf)
{
    extern __shared__ char sm[];  // [0,32768): sW2T swizzled bf16; [32768,65536): sH1 swizzled bf16
    const int tid  = threadIdx.x;
    const int b    = blockIdx.x >> 5;
    const int c    = blockIdx.x & 31;
    const int lane = tid & 63;
    const int w    = tid >> 6;
    const int lr   = lane & 15;
    const int lk   = lane >> 4;
    const int swz  = (lr & 7) << 4;
    char* sH1 = sm + 32768;

    // stage W2T into LDS, XOR-swizzled: linear byte lb -> lb ^ ((row&7)<<4), row = lb>>8
    {
        const float4* src = (const float4*)w2t;  // 2048 x 16B
        #pragma unroll
        for (int it = 0; it < 8; ++it) {
            int cch = tid + it * 256;
            int lb  = cch << 4;
            int dst = lb ^ (((cch >> 4) & 7) << 4);
            *(float4*)(sm + dst) = src[cch];
        }
    }

    // hoist per-thread constants
    const int fg = tid & 31, tg = tid >> 5;
    const int f0 = fg << 2;
    float w10[4], w11[4], bb1[4];
    #pragma unroll
    for (int i = 0; i < 4; ++i) {
        w10[i] = W1[f0 + i];
        w11[i] = W1[128 + f0 + i];
        bb1[i] = b1[f0 + i];
    }
    float b2r[8];
    #pragma unroll
    for (int nt = 0; nt < 8; ++nt) b2r[nt] = b2[nt * 16 + lr];

    float runS[8], runM[8];
    #pragma unroll
    for (int nt = 0; nt < 8; ++nt) { runS[nt] = 0.0f; runM[nt] = -3.0e38f; }

    const float2* xr = (const float2*)x + (size_t)b * L_LEN;

    __syncthreads();

    for (int tile = 0; tile < NTILES; ++tile) {
        const int gt = c * CHUNK + tile * TILE_T;

        // ---- h1 phase: thread -> tokens tg*16..+15, features f0..f0+3 ----
        {
            int t0 = tg * 16;
            float2 a0 = xr[gt + t0];
            #pragma unroll
            for (int tt = 0; tt < 16; ++tt) {
                int t  = t0 + tt;
                int ln = gt + t + 1;
                if (ln == L_LEN) ln = 0;          // circular roll over L
                float2 a1 = xr[ln];
                float dx0 = a1.x - a0.x, dx1 = a1.y - a0.y;
                float h0 = gelu_f(fmaf(dx0, w10[0], fmaf(dx1, w11[0], bb1[0])));
                float h1v = gelu_f(fmaf(dx0, w10[1], fmaf(dx1, w11[1], bb1[1])));
                float h2v = gelu_f(fmaf(dx0, w10[2], fmaf(dx1, w11[2], bb1[2])));
                float h3 = gelu_f(fmaf(dx0, w10[3], fmaf(dx1, w11[3], bb1[3])));
                unsigned p0 = (unsigned)f2bf(h0)  | ((unsigned)f2bf(h1v) << 16);
                unsigned p1 = (unsigned)f2bf(h2v) | ((unsigned)f2bf(h3)  << 16);
                int off = (t << 8) + (fg << 3);
                off ^= (t & 7) << 4;
                uint2 pk; pk.x = p0; pk.y = p1;
                *(uint2*)(sH1 + off) = pk;
                a0 = a1;
            }
        }
        __syncthreads();

        // ---- GEMM: wave w -> tokens w*32..+31, all 128 features ----
        {
            f32x4 acc[2][8];
            #pragma unroll
            for (int rb = 0; rb < 2; ++rb)
                #pragma unroll
                for (int nt = 0; nt < 8; ++nt)
                    acc[rb][nt] = (f32x4){0.f, 0.f, 0.f, 0.f};

            #pragma unroll
            for (int kt = 0; kt < 4; ++kt) {
                bf16x8 aF[2];
                #pragma unroll
                for (int rb = 0; rb < 2; ++rb) {
                    int row = w * 32 + rb * 16 + lr;
                    int ao  = (row << 8) + kt * 64 + (lk << 4);
                    ao ^= swz;
                    aF[rb] = *(const bf16x8*)(sH1 + ao);
                }
                #pragma unroll
                for (int nt = 0; nt < 8; ++nt) {
                    int col = nt * 16 + lr;
                    int bo  = (col << 8) + kt * 64 + (lk << 4);
                    bo ^= swz;
                    bf16x8 bF = *(const bf16x8*)(sm + bo);
                    acc[0][nt] = __builtin_amdgcn_mfma_f32_16x16x32_bf16(aF[0], bF, acc[0][nt], 0, 0, 0);
                    acc[1][nt] = __builtin_amdgcn_mfma_f32_16x16x32_bf16(aF[1], bF, acc[1][nt], 0, 0, 0);
                }
            }

            // ---- epilogue: +b2, gelu, per-feature sum/max over wave's 32 tokens ----
            #pragma unroll
            for (int nt = 0; nt < 8; ++nt) {
                float s = 0.0f, m = -3.0e38f;
                #pragma unroll
                for (int rb = 0; rb < 2; ++rb) {
                    #pragma unroll
                    for (int r = 0; r < 4; ++r) {
                        float v = gelu_f(acc[rb][nt][r] + b2r[nt]);
                        s += v;
                        m = fmaxf(m, v);
                    }
                }
                s += __shfl_xor(s, 16, 64);
                s += __shfl_xor(s, 32, 64);
                m = fmaxf(m, __shfl_xor(m, 16, 64));
                m = fmaxf(m, __shfl_xor(m, 32, 64));
                runS[nt] += s;
                runM[nt] = fmaxf(runM[nt], m);
            }
        }
        __syncthreads();
    }

    // ---- cross-wave combine via scratch overlaying sH1 (GEMM reads done) ----
    float* scrS = (float*)(sm + 32768);         // [4][128]
    float* scrM = (float*)(sm + 32768 + 2048);  // [4][128]
    if (lk == 0) {
        #pragma unroll
        for (int nt = 0; nt < 8; ++nt) {
            scrS[w * 128 + nt * 16 + lr] = runS[nt];
            scrM[w * 128 + nt * 16 + lr] = runM[nt];
        }
    }
    __syncthreads();
    if (tid < 128) {
        float s = (scrS[tid] + scrS[128 + tid]) + (scrS[256 + tid] + scrS[384 + tid]);
        float m = fmaxf(fmaxf(scrM[tid], scrM[128 + tid]), fmaxf(scrM[256 + tid], scrM[384 + tid]));
        int o = (b * NCHUNK + c) * 128 + tid;
        psum[o]  = s;
        pmaxf[o] = m;
    }
}

// K2: reduce chunks -> mean/max -> z = cat@Wh + bh -> LayerNorm -> out
__global__ __launch_bounds__(128) void k2_final(
    const float* __restrict__ psum,
    const float* __restrict__ pmaxf,
    const float* __restrict__ Wh,
    const float* __restrict__ bh,
    const float* __restrict__ gamma,
    const float* __restrict__ beta,
    float* __restrict__ out)
{
    __shared__ float cat[256];
    __shared__ float red[4];
    const int b = blockIdx.x, f = threadIdx.x;
    float s = 0.0f, m = -3.0e38f;
    #pragma unroll
    for (int c = 0; c < NCHUNK; ++c) {
        int o = (b * NCHUNK + c) * 128 + f;
        s += psum[o];
        m = fmaxf(m, pmaxf[o]);
    }
    cat[f]       = s * (1.0f / 16384.0f);
    cat[128 + f] = m;
    __syncthreads();

    float z = bh[f];
    #pragma unroll 4
    for (int j = 0; j < 256; ++j) z = fmaf(cat[j], Wh[j * 128 + f], z);

    float s1 = z, s2 = z * z;
    #pragma unroll
    for (int off = 32; off >= 1; off >>= 1) {
        s1 += __shfl_xor(s1, off, 64);
        s2 += __shfl_xor(s2, off, 64);
    }
    int lane = f & 63, wv = f >> 6;
    if (lane == 0) { red[wv] = s1; red[2 + wv] = s2; }
    __syncthreads();
    float S1 = red[0] + red[1], S2 = red[2] + red[3];
    float mu  = S1 * (1.0f / 128.0f);
    float var = S2 * (1.0f / 128.0f) - mu * mu;
    out[b * 128 + f] = (z - mu) * rsqrtf(var + 1e-5f) * gamma[f] + beta[f];
}

extern "C" void kernel_launch(void* const* d_in, const int* in_sizes, int n_in,
                              void* d_out, int out_size, void* d_ws, size_t ws_size,
                              hipStream_t stream) {
    const float* x     = (const float*)d_in[0];
    const float* W1    = (const float*)d_in[1];
    const float* b1    = (const float*)d_in[2];
    const float* W2    = (const float*)d_in[3];
    const float* b2    = (const float*)d_in[4];
    const float* Wh    = (const float*)d_in[5];
    const float* bh    = (const float*)d_in[6];
    const float* gamma = (const float*)d_in[7];
    const float* beta  = (const float*)d_in[8];
    float* out = (float*)d_out;

    char* wsb = (char*)d_ws;
    unsigned short* w2t = (unsigned short*)wsb;                         // 32 KiB
    float* psum  = (float*)(wsb + 32768);                               // 1 MiB
    float* pmaxf = (float*)(wsb + 32768 + NB * NCHUNK * 128 * 4);       // 1 MiB

    k0_prep<<<64, 256, 0, stream>>>(W2, w2t);
    k1_fused<<<NB * NCHUNK, 256, 65536, stream>>>(x, W1, b1, w2t, b2, psum, pmaxf);
    k2_final<<<NB, 128, 0, stream>>>(psum, pmaxf, Wh, bh, gamma, beta, out);
}